// Round 12
// baseline (150.421 us; speedup 1.0000x reference)
//
#include <hip/hip_runtime.h>
#include <math.h>

// Problem constants
#define BB    16      // batch
#define CC    64      // channels
#define HW    441     // h*w
#define QP    448     // HW padded to 28 tiles of 16
#define NCLS  10
#define MM    2205
#define MP2   2304    // m padded to 144 tiles of 16
#define NQT   2       // q-tiles per block (32 queries) — live pressure < 64 VGPR
#define NQG   14      // q-groups (14 x 32 = 448)

typedef _Float16 half8 __attribute__((ext_vector_type(8)));
typedef float   float4_ __attribute__((ext_vector_type(4)));

// sorted top-3 insert (a0>=a1>=a2): 3 ops via med3
__device__ __forceinline__ void ins3(float d, float& a0, float& a1, float& a2) {
    float n0 = fmaxf(d, a0);
    float n1 = __builtin_amdgcn_fmed3f(d, a0, a1);
    float n2 = __builtin_amdgcn_fmed3f(d, a1, a2);
    a0 = n0; a1 = n1; a2 = n2;
}

// ---- fused prep: normalize queries + supports to fp16 in LINEAR [m][channel]
// layout (no swizzle — S is consumed by per-lane global loads now, not LDS),
// with LDS-transposed fully-coalesced 4KB block stores ----
__global__ __launch_bounds__(256) void prep(const float* __restrict__ x1,
                                            const float* __restrict__ x2,
                                            _Float16* __restrict__ qn,
                                            _Float16* __restrict__ sn) {
    __shared__ float ssred[256];
    __shared__ half8 obuf[256];     // 32 descriptors x 8 pieces = 4KB
    int tid = threadIdx.x;
    int ml = tid & 31, cg = tid >> 5;     // 32 descriptors x 8 c-groups
    float v[8];
    half8* dstblk;
    if (blockIdx.x < BB * 14) {           // queries: 16 b x 14 p-tiles of 32
        int b = blockIdx.x / 14, pt = blockIdx.x % 14;
        int p = pt * 32 + ml;
        const float* src = x1 + (size_t)b * CC * HW + p;
        bool real = p < HW;
        #pragma unroll
        for (int i = 0; i < 8; ++i) v[i] = real ? src[(size_t)(cg * 8 + i) * HW] : 0.f;
        dstblk = (half8*)(qn + ((size_t)(b * QP + pt * 32)) * CC);
    } else {                              // supports: 10 n x 72 m-tiles of 32
        int sb = blockIdx.x - BB * 14;
        int n = sb / 72, mt = sb % 72;
        int m = mt * 32 + ml;
        const float* src = x2 + (size_t)n * CC * MM + m;
        bool real = m < MM;
        #pragma unroll
        for (int i = 0; i < 8; ++i) v[i] = real ? src[(size_t)(cg * 8 + i) * MM] : 0.f;
        dstblk = (half8*)(sn + ((size_t)(n * MP2 + mt * 32)) * CC);
    }
    float ss = 0.f;
    #pragma unroll
    for (int i = 0; i < 8; ++i) ss += v[i] * v[i];
    ssred[tid] = ss;
    __syncthreads();
    float tot = 0.f;
    #pragma unroll
    for (int j = 0; j < 8; ++j) tot += ssred[j * 32 + ml];
    float inv = 1.f / fmaxf(sqrtf(tot), 1e-12f);
    half8 h;
    #pragma unroll
    for (int i = 0; i < 8; ++i) h[i] = (_Float16)(v[i] * inv);
    obuf[ml * 8 + cg] = h;                // [descriptor][piece] linear
    __syncthreads();
    dstblk[tid] = obuf[tid];              // 256 x 16B contiguous
}

// ---- main: per-(b,n,qgroup,mhalf) block. Swapped-operand MFMA D[m][q].
// NO LDS STAGING: each lane's S-fragment is lane-private MFMA input, so it
// is loaded DIRECTLY from L2 with plain global loads (fully coalesced at
// cache-line granularity). No global_load_lds / vmcnt / sched_barrier /
// double-buffer — the constructs rounds 7-11 showed this pool's compilers
// mishandle (spill 200-540MB, 156-VGPR hoist, 52-VGPR remat). Live set
// ~55 VGPR < 64 -> up to 8 waves/SIMD; latency hidden by TLP, not by a
// hand-built pipeline. 4 waves split m (2 tiles/iter each, 9 iters/half). ----
__global__ __launch_bounds__(256) void img2class_mfma(const _Float16* __restrict__ qn,
                                                      const _Float16* __restrict__ sn,
                                                      float* __restrict__ partial) {
    __shared__ float dump[4][NQT * 16][3];   // 1.5KB — epilogue only

    int mh = blockIdx.x & 1;
    int t  = blockIdx.x >> 1;
    int bn = t / NQG, qg = t % NQG;
    int b = bn / NCLS, n = bn % NCLS;
    int mtile0 = mh ? 72 : 0;

    int tid  = threadIdx.x;
    int wave = tid >> 6, lane = tid & 63;
    int col  = lane & 15, quad = lane >> 4;
    int q0 = qg * (NQT * 16);

    // Q fragments: 2 q-tiles x (k 0-31 | 32-63), register-resident (16 VGPR).
    // B-operand layout: col j = lane&15 (query), k = quad*8+i.
    const half8* Qp = (const half8*)(qn + ((size_t)(b * QP + q0 + col)) * CC) + quad;
    half8 Q0[NQT], Q1[NQT];
    #pragma unroll
    for (int qt = 0; qt < NQT; ++qt) {
        Q0[qt] = Qp[qt * 128];
        Q1[qt] = Qp[qt * 128 + 4];
    }

    // per-lane top-3 per q-tile (lane's q = q0 + qt*16 + col)
    float T0[NQT], T1[NQT], T2[NQT];
    #pragma unroll
    for (int qt = 0; qt < NQT; ++qt) { T0[qt] = -1.0e30f; T1[qt] = -1.0e30f; T2[qt] = -1.0e30f; }

    // lane's S base for its wave's first even tile: [m][channel] linear.
    // A-operand layout: row i = col (descriptor), k = quad*8+j -> lane reads
    // 16B at (tile*16+col)*CC + quad*8, and piece 4+quad at +32 halves.
    const _Float16* sp = sn + ((size_t)n * MP2 + (size_t)(mtile0 + wave * 2) * 16) * CC
                            + col * CC + quad * 8;

    #pragma clang loop unroll(disable)
    for (int c = 0; c < 9; ++c) {
        half8 S0e = *(const half8*)(sp);
        half8 S1e = *(const half8*)(sp + 32);
        half8 S0o = *(const half8*)(sp + 16 * CC);
        half8 S1o = *(const half8*)(sp + 16 * CC + 32);

        // pad penalty (only last iter of half1 reaches m >= MM; wave-uniform)
        int tE = mtile0 + c * 8 + wave * 2;
        bool dopen = (tE >= 136);
        float pE0 = 0.f, pE1 = 0.f, pE2 = 0.f, pE3 = 0.f;
        float pO0 = 0.f, pO1 = 0.f, pO2 = 0.f, pO3 = 0.f;
        if (dopen) {
            int mE = tE * 16 + quad * 4;
            pE0 = (mE +  0 >= MM) ? -1.0e30f : 0.f;
            pE1 = (mE +  1 >= MM) ? -1.0e30f : 0.f;
            pE2 = (mE +  2 >= MM) ? -1.0e30f : 0.f;
            pE3 = (mE +  3 >= MM) ? -1.0e30f : 0.f;
            pO0 = (mE + 16 >= MM) ? -1.0e30f : 0.f;
            pO1 = (mE + 17 >= MM) ? -1.0e30f : 0.f;
            pO2 = (mE + 18 >= MM) ? -1.0e30f : 0.f;
            pO3 = (mE + 19 >= MM) ? -1.0e30f : 0.f;
        }

        float4_ z = {0.f, 0.f, 0.f, 0.f};
        #pragma unroll
        for (int qt = 0; qt < NQT; ++qt) {
            // D[i=m][j=q]: rows quad*4+r are m within tile, col = q within tile
            float4_ ae = __builtin_amdgcn_mfma_f32_16x16x32_f16(S0e, Q0[qt], z, 0, 0, 0);
            ae = __builtin_amdgcn_mfma_f32_16x16x32_f16(S1e, Q1[qt], ae, 0, 0, 0);
            float4_ ao = __builtin_amdgcn_mfma_f32_16x16x32_f16(S0o, Q0[qt], z, 0, 0, 0);
            ao = __builtin_amdgcn_mfma_f32_16x16x32_f16(S1o, Q1[qt], ao, 0, 0, 0);
            if (dopen) {
                ae.x += pE0; ae.y += pE1; ae.z += pE2; ae.w += pE3;
                ao.x += pO0; ao.y += pO1; ao.z += pO2; ao.w += pO3;
            }
            // pair-max filter over adjacent tiles (m, m+16) — identical
            // candidate multiset to all prior passing kernels — then 3-op inserts
            float d0 = fmaxf(ae.x, ao.x);
            float d1 = fmaxf(ae.y, ao.y);
            float d2 = fmaxf(ae.z, ao.z);
            float d3 = fmaxf(ae.w, ao.w);
            ins3(d0, T0[qt], T1[qt], T2[qt]);
            ins3(d1, T0[qt], T1[qt], T2[qt]);
            ins3(d2, T0[qt], T1[qt], T2[qt]);
            ins3(d3, T0[qt], T1[qt], T2[qt]);
        }

        sp += 8 * 16 * CC;   // advance 8 tiles (loop-carried, no recompute)
    }

    // merge across the 4 quads (disjoint m rows, same q): 2-step butterfly
    #pragma unroll
    for (int step = 16; step <= 32; step <<= 1) {
        #pragma unroll
        for (int qt = 0; qt < NQT; ++qt) {
            float o0 = __shfl_xor(T0[qt], step);
            float o1 = __shfl_xor(T1[qt], step);
            float o2 = __shfl_xor(T2[qt], step);
            ins3(o0, T0[qt], T1[qt], T2[qt]);
            ins3(o1, T0[qt], T1[qt], T2[qt]);
            ins3(o2, T0[qt], T1[qt], T2[qt]);
        }
    }

    // dump per-wave per-q top-3, then cross-wave merge (waves hold disjoint m)
    if (quad == 0) {
        #pragma unroll
        for (int qt = 0; qt < NQT; ++qt) {
            dump[wave][qt * 16 + col][0] = T0[qt];
            dump[wave][qt * 16 + col][1] = T1[qt];
            dump[wave][qt * 16 + col][2] = T2[qt];
        }
    }
    __syncthreads();

    if (tid < NQT * 16) {
        float a0 = dump[0][tid][0], a1 = dump[0][tid][1], a2 = dump[0][tid][2];
        #pragma unroll
        for (int w = 1; w < 4; ++w) {
            ins3(dump[w][tid][0], a0, a1, a2);
            ins3(dump[w][tid][1], a0, a1, a2);
            ins3(dump[w][tid][2], a0, a1, a2);
        }
        float* pp = partial + ((size_t)((bn * NQG + qg) * 2 + mh) * (NQT * 16) + tid) * 3;
        pp[0] = a0; pp[1] = a1; pp[2] = a2;
    }
}

// ---- merge the two m-halves per query, sum top-3, reduce over queries ----
__global__ __launch_bounds__(512) void merge_halves(const float* __restrict__ partial,
                                                    float* __restrict__ out) {
    __shared__ float red[512];
    int bn = blockIdx.x;
    int q  = threadIdx.x;
    float s = 0.f;
    if (q < HW) {
        int qg = q >> 5, ql = q & 31;
        const float* p0 = partial + ((size_t)((bn * NQG + qg) * 2 + 0) * 32 + ql) * 3;
        const float* p1 = partial + ((size_t)((bn * NQG + qg) * 2 + 1) * 32 + ql) * 3;
        float a0 = p0[0], a1 = p0[1], a2 = p0[2];
        ins3(p1[0], a0, a1, a2);
        ins3(p1[1], a0, a1, a2);
        ins3(p1[2], a0, a1, a2);
        s = a0 + a1 + a2;
    }
    red[q] = s;
    __syncthreads();
    #pragma unroll
    for (int stride = 256; stride >= 1; stride >>= 1) {
        if (q < stride) red[q] += red[q + stride];
        __syncthreads();
    }
    if (q == 0) out[bn] = red[0];
}

extern "C" void kernel_launch(void* const* d_in, const int* in_sizes, int n_in,
                              void* d_out, int out_size, void* d_ws, size_t ws_size,
                              hipStream_t stream) {
    const float* x1 = (const float*)d_in[0];   // [16,64,21,21]
    const float* x2 = (const float*)d_in[1];   // [10,64,2205]
    float* out = (float*)d_out;                // [16,10]

    _Float16* qn   = (_Float16*)d_ws;                  // 16*448*64 halves
    _Float16* sn   = qn + (size_t)BB * QP * CC;        // 10*2304*64 halves, linear
    float* partial = (float*)(sn + (size_t)NCLS * MP2 * CC);  // 4480*32*3 floats

    prep<<<BB * 14 + NCLS * 72, 256, 0, stream>>>(x1, x2, qn, sn);
    img2class_mfma<<<BB * NCLS * NQG * 2, 256, 0, stream>>>(qn, sn, partial);
    merge_halves<<<BB * NCLS, 512, 0, stream>>>(partial, out);
}

// Round 13
// 119.543 us; speedup vs baseline: 1.2583x; 1.2583x over previous
//
#include <hip/hip_runtime.h>
#include <math.h>

// Problem constants
#define BB    16      // batch
#define CC    64      // channels
#define HW    441     // h*w
#define QP    448     // HW padded to 28 tiles of 16
#define NCLS  10
#define MM    2205
#define MP2   2304    // m padded to 144 tiles of 16
#define NQT   4       // q-tiles per block (64 queries)
#define NQG   7       // q-groups (7 x 64 = 448)

typedef _Float16 half8 __attribute__((ext_vector_type(8)));
typedef float   float4_ __attribute__((ext_vector_type(4)));

// sorted top-3 insert (a0>=a1>=a2): 3 ops via med3
__device__ __forceinline__ void ins3(float d, float& a0, float& a1, float& a2) {
    float n0 = fmaxf(d, a0);
    float n1 = __builtin_amdgcn_fmed3f(d, a0, a1);
    float n2 = __builtin_amdgcn_fmed3f(d, a1, a2);
    a0 = n0; a1 = n1; a2 = n2;
}

// ---- fused prep: normalize queries + supports to fp16 in LINEAR [m][channel]
// layout (S is consumed by per-lane global loads, not LDS), with
// LDS-transposed fully-coalesced 4KB block stores ----
__global__ __launch_bounds__(256) void prep(const float* __restrict__ x1,
                                            const float* __restrict__ x2,
                                            _Float16* __restrict__ qn,
                                            _Float16* __restrict__ sn) {
    __shared__ float ssred[256];
    __shared__ half8 obuf[256];     // 32 descriptors x 8 pieces = 4KB
    int tid = threadIdx.x;
    int ml = tid & 31, cg = tid >> 5;     // 32 descriptors x 8 c-groups
    float v[8];
    half8* dstblk;
    if (blockIdx.x < BB * 14) {           // queries: 16 b x 14 p-tiles of 32
        int b = blockIdx.x / 14, pt = blockIdx.x % 14;
        int p = pt * 32 + ml;
        const float* src = x1 + (size_t)b * CC * HW + p;
        bool real = p < HW;
        #pragma unroll
        for (int i = 0; i < 8; ++i) v[i] = real ? src[(size_t)(cg * 8 + i) * HW] : 0.f;
        dstblk = (half8*)(qn + ((size_t)(b * QP + pt * 32)) * CC);
    } else {                              // supports: 10 n x 72 m-tiles of 32
        int sb = blockIdx.x - BB * 14;
        int n = sb / 72, mt = sb % 72;
        int m = mt * 32 + ml;
        const float* src = x2 + (size_t)n * CC * MM + m;
        bool real = m < MM;
        #pragma unroll
        for (int i = 0; i < 8; ++i) v[i] = real ? src[(size_t)(cg * 8 + i) * MM] : 0.f;
        dstblk = (half8*)(sn + ((size_t)(n * MP2 + mt * 32)) * CC);
    }
    float ss = 0.f;
    #pragma unroll
    for (int i = 0; i < 8; ++i) ss += v[i] * v[i];
    ssred[tid] = ss;
    __syncthreads();
    float tot = 0.f;
    #pragma unroll
    for (int j = 0; j < 8; ++j) tot += ssred[j * 32 + ml];
    float inv = 1.f / fmaxf(sqrtf(tot), 1e-12f);
    half8 h;
    #pragma unroll
    for (int i = 0; i < 8; ++i) h[i] = (_Float16)(v[i] * inv);
    obuf[ml * 8 + cg] = h;                // [descriptor][piece] linear
    __syncthreads();
    dstblk[tid] = obuf[tid];              // 256 x 16B contiguous
}

// ---- main: per-(b,n,qgroup,mhalf) block. Swapped-operand MFMA D[m][q].
// Direct-from-L2 per-lane S loads (no LDS staging, no global_load_lds /
// vmcnt / sched_barrier — the constructs this pool's compilers mishandle).
// REGISTER PREFETCH double-buffer: iteration c+1's four S-fragments are
// loaded into N* before computing iteration c, overlapping ~250-cycle L2
// latency with 16 MFMAs (round 12's 9% MfmaUtil was a serial load->use
// chain). NQT=4 halves L2 traffic vs round 12 and doubles MFMA per load.
// 4 waves split m (2 adjacent tiles per iter each, 9 iters per m-half). ----
__global__ __launch_bounds__(256) void img2class_mfma(const _Float16* __restrict__ qn,
                                                      const _Float16* __restrict__ sn,
                                                      float* __restrict__ partial) {
    __shared__ float dump[4][NQT * 16][3];   // 3KB — epilogue only

    int mh = blockIdx.x & 1;
    int t  = blockIdx.x >> 1;
    int bn = t / NQG, qg = t % NQG;
    int b = bn / NCLS, n = bn % NCLS;
    int mtile0 = mh ? 72 : 0;

    int tid  = threadIdx.x;
    int wave = tid >> 6, lane = tid & 63;
    int col  = lane & 15, quad = lane >> 4;
    int q0 = qg * (NQT * 16);

    // Q fragments: 4 q-tiles x (k 0-31 | 32-63), register-resident (32 VGPR).
    // B-operand layout: col j = lane&15 (query), k = quad*8+i.
    const half8* Qp = (const half8*)(qn + ((size_t)(b * QP + q0 + col)) * CC) + quad;
    half8 Q0[NQT], Q1[NQT];
    #pragma unroll
    for (int qt = 0; qt < NQT; ++qt) {
        Q0[qt] = Qp[qt * 128];
        Q1[qt] = Qp[qt * 128 + 4];
    }

    // per-lane top-3 per q-tile (lane's q = q0 + qt*16 + col)
    float T0[NQT], T1[NQT], T2[NQT];
    #pragma unroll
    for (int qt = 0; qt < NQT; ++qt) { T0[qt] = -1.0e30f; T1[qt] = -1.0e30f; T2[qt] = -1.0e30f; }

    // lane's S base for its wave's first even tile: [m][channel] linear.
    // A-operand layout: row i = col (descriptor), k = quad*8+j -> lane reads
    // 16B at (tile*16+col)*CC + quad*8, and piece 4+quad at +32 halves.
    const _Float16* sp = sn + ((size_t)n * MP2 + (size_t)(mtile0 + wave * 2) * 16) * CC
                            + col * CC + quad * 8;

    // preload iteration 0
    half8 S0e = *(const half8*)(sp);
    half8 S1e = *(const half8*)(sp + 32);
    half8 S0o = *(const half8*)(sp + 16 * CC);
    half8 S1o = *(const half8*)(sp + 16 * CC + 32);

    #pragma clang loop unroll(disable)
    for (int c = 0; c < 9; ++c) {
        // issue next-iteration loads FIRST (register prefetch; clamp on last)
        const _Float16* spn = sp + (c + 1 < 9 ? 8 * 16 * CC : 0);
        half8 N0e = *(const half8*)(spn);
        half8 N1e = *(const half8*)(spn + 32);
        half8 N0o = *(const half8*)(spn + 16 * CC);
        half8 N1o = *(const half8*)(spn + 16 * CC + 32);

        // pad penalty (only last iter of half1 reaches m >= MM; wave-uniform)
        int tE = mtile0 + c * 8 + wave * 2;
        bool dopen = (tE >= 136);
        float pE0 = 0.f, pE1 = 0.f, pE2 = 0.f, pE3 = 0.f;
        float pO0 = 0.f, pO1 = 0.f, pO2 = 0.f, pO3 = 0.f;
        if (dopen) {
            int mE = tE * 16 + quad * 4;
            pE0 = (mE +  0 >= MM) ? -1.0e30f : 0.f;
            pE1 = (mE +  1 >= MM) ? -1.0e30f : 0.f;
            pE2 = (mE +  2 >= MM) ? -1.0e30f : 0.f;
            pE3 = (mE +  3 >= MM) ? -1.0e30f : 0.f;
            pO0 = (mE + 16 >= MM) ? -1.0e30f : 0.f;
            pO1 = (mE + 17 >= MM) ? -1.0e30f : 0.f;
            pO2 = (mE + 18 >= MM) ? -1.0e30f : 0.f;
            pO3 = (mE + 19 >= MM) ? -1.0e30f : 0.f;
        }

        float4_ z = {0.f, 0.f, 0.f, 0.f};
        #pragma unroll
        for (int qt = 0; qt < NQT; ++qt) {
            // D[i=m][j=q]: rows quad*4+r are m within tile, col = q within tile
            float4_ ae = __builtin_amdgcn_mfma_f32_16x16x32_f16(S0e, Q0[qt], z, 0, 0, 0);
            ae = __builtin_amdgcn_mfma_f32_16x16x32_f16(S1e, Q1[qt], ae, 0, 0, 0);
            float4_ ao = __builtin_amdgcn_mfma_f32_16x16x32_f16(S0o, Q0[qt], z, 0, 0, 0);
            ao = __builtin_amdgcn_mfma_f32_16x16x32_f16(S1o, Q1[qt], ao, 0, 0, 0);
            if (dopen) {
                ae.x += pE0; ae.y += pE1; ae.z += pE2; ae.w += pE3;
                ao.x += pO0; ao.y += pO1; ao.z += pO2; ao.w += pO3;
            }
            // pair-max filter over adjacent tiles (m, m+16) — identical
            // candidate multiset to all prior passing kernels — then inserts
            float d0 = fmaxf(ae.x, ao.x);
            float d1 = fmaxf(ae.y, ao.y);
            float d2 = fmaxf(ae.z, ao.z);
            float d3 = fmaxf(ae.w, ao.w);
            ins3(d0, T0[qt], T1[qt], T2[qt]);
            ins3(d1, T0[qt], T1[qt], T2[qt]);
            ins3(d2, T0[qt], T1[qt], T2[qt]);
            ins3(d3, T0[qt], T1[qt], T2[qt]);
        }

        // rotate prefetch into place (register PHIs, no recompute)
        S0e = N0e; S1e = N1e; S0o = N0o; S1o = N1o;
        sp = spn;
    }

    // merge across the 4 quads (disjoint m rows, same q): 2-step butterfly
    #pragma unroll
    for (int step = 16; step <= 32; step <<= 1) {
        #pragma unroll
        for (int qt = 0; qt < NQT; ++qt) {
            float o0 = __shfl_xor(T0[qt], step);
            float o1 = __shfl_xor(T1[qt], step);
            float o2 = __shfl_xor(T2[qt], step);
            ins3(o0, T0[qt], T1[qt], T2[qt]);
            ins3(o1, T0[qt], T1[qt], T2[qt]);
            ins3(o2, T0[qt], T1[qt], T2[qt]);
        }
    }

    // dump per-wave per-q top-3, then cross-wave merge (waves hold disjoint m)
    if (quad == 0) {
        #pragma unroll
        for (int qt = 0; qt < NQT; ++qt) {
            dump[wave][qt * 16 + col][0] = T0[qt];
            dump[wave][qt * 16 + col][1] = T1[qt];
            dump[wave][qt * 16 + col][2] = T2[qt];
        }
    }
    __syncthreads();

    if (tid < NQT * 16) {
        float a0 = dump[0][tid][0], a1 = dump[0][tid][1], a2 = dump[0][tid][2];
        #pragma unroll
        for (int w = 1; w < 4; ++w) {
            ins3(dump[w][tid][0], a0, a1, a2);
            ins3(dump[w][tid][1], a0, a1, a2);
            ins3(dump[w][tid][2], a0, a1, a2);
        }
        float* pp = partial + ((size_t)((bn * NQG + qg) * 2 + mh) * (NQT * 16) + tid) * 3;
        pp[0] = a0; pp[1] = a1; pp[2] = a2;
    }
}

// ---- merge the two m-halves per query, sum top-3, reduce over queries ----
__global__ __launch_bounds__(512) void merge_halves(const float* __restrict__ partial,
                                                    float* __restrict__ out) {
    __shared__ float red[512];
    int bn = blockIdx.x;
    int q  = threadIdx.x;
    float s = 0.f;
    if (q < HW) {
        int qg = q >> 6, ql = q & 63;
        const float* p0 = partial + ((size_t)((bn * NQG + qg) * 2 + 0) * 64 + ql) * 3;
        const float* p1 = partial + ((size_t)((bn * NQG + qg) * 2 + 1) * 64 + ql) * 3;
        float a0 = p0[0], a1 = p0[1], a2 = p0[2];
        ins3(p1[0], a0, a1, a2);
        ins3(p1[1], a0, a1, a2);
        ins3(p1[2], a0, a1, a2);
        s = a0 + a1 + a2;
    }
    red[q] = s;
    __syncthreads();
    #pragma unroll
    for (int stride = 256; stride >= 1; stride >>= 1) {
        if (q < stride) red[q] += red[q + stride];
        __syncthreads();
    }
    if (q == 0) out[bn] = red[0];
}

extern "C" void kernel_launch(void* const* d_in, const int* in_sizes, int n_in,
                              void* d_out, int out_size, void* d_ws, size_t ws_size,
                              hipStream_t stream) {
    const float* x1 = (const float*)d_in[0];   // [16,64,21,21]
    const float* x2 = (const float*)d_in[1];   // [10,64,2205]
    float* out = (float*)d_out;                // [16,10]

    _Float16* qn   = (_Float16*)d_ws;                  // 16*448*64 halves
    _Float16* sn   = qn + (size_t)BB * QP * CC;        // 10*2304*64 halves, linear
    float* partial = (float*)(sn + (size_t)NCLS * MP2 * CC);  // 2240*64*3 floats

    prep<<<BB * 14 + NCLS * 72, 256, 0, stream>>>(x1, x2, qn, sn);
    img2class_mfma<<<BB * NCLS * NQG * 2, 256, 0, stream>>>(qn, sn, partial);
    merge_halves<<<BB * NCLS, 512, 0, stream>>>(partial, out);
}